// Round 14
// baseline (109.178 us; speedup 1.0000x reference)
//
#include <hip/hip_runtime.h>
#include <hip/hip_bf16.h>

typedef short bf16x8 __attribute__((ext_vector_type(8)));
typedef float f32x4 __attribute__((ext_vector_type(4)));

#define N_USER 50000
#define N_ITEM 50000
#define IN_DIM 256
#define HID 128
#define OUT_DIM 64
#define NEDGE 200000
#define CAP 32
#define NSTRIP 3125    // 50000/16
#define PROJ_GRID 391  // ceil(6250 strips / 16 waves)

__device__ __forceinline__ float bf2f(unsigned short u) {
    union { unsigned int i; float f; } v; v.i = ((unsigned int)u) << 16; return v.f;
}
__device__ __forceinline__ unsigned short f2bf(float f) {
    union { float f; unsigned int i; } v; v.f = f;
    return (unsigned short)((v.i + 0x7fffu + ((v.i >> 16) & 1u)) >> 16);
}
__device__ __forceinline__ unsigned int cvt_pk_bf16(float a, float b) {
    unsigned int r;
    asm("v_cvt_pk_bf16_f32 %0, %1, %2" : "=v"(r) : "v"(a), "v"(b));
    return r;
}
__device__ __forceinline__ float elu_f(float x) {
    return x > 0.f ? x : (__expf(x) - 1.f);
}

// ---- pack weights (frag order) + zero cnt, one launch ----
__global__ __launch_bounds__(256) void pack_w_kernel(
    const float* __restrict__ Wp, const float* __restrict__ Wo,
    unsigned short* __restrict__ Wpk, unsigned short* __restrict__ Wok,
    int* __restrict__ cnt)
{
    int bid = blockIdx.x;
    if (bid >= 20) {
        int idx = (bid - 20) * 256 + threadIdx.x;
        if (idx < 3 * N_USER) cnt[idx] = 0;
        return;
    }
    int t = bid * 256 + threadIdx.x;
    if (t < 4096) {
        int lane = t & 63, kb = (t >> 6) & 7, nt = t >> 9;
        int r = lane & 15, kg = lane >> 4;
        unsigned short o[8];
        #pragma unroll
        for (int j = 0; j < 8; ++j)
            o[j] = f2bf(Wp[(size_t)(kb * 32 + kg * 8 + j) * HID + nt * 16 + r]);
        for (int cp = 0; cp < 8; ++cp) {
            #pragma unroll
            for (int j = 0; j < 8; ++j) Wpk[cp * 32768 + t * 8 + j] = o[j];
        }
    } else if (t < 4096 + 1024) {
        int q = t - 4096;
        int lane = q & 63, kb = (q >> 6) & 3, nt = q >> 8;
        int r = lane & 15, kg = lane >> 4;
        unsigned short o[8];
        #pragma unroll
        for (int j = 0; j < 8; ++j)
            o[j] = f2bf(Wo[(size_t)(j * 16 + kb * 4 + kg) * OUT_DIM + nt * 16 + r]);
        #pragma unroll
        for (int j = 0; j < 8; ++j) Wok[q * 8 + j] = o[j];
    }
}

// Standalone bucket fill: one thread per edge, max TLP, no LDS (R11's 8µs config).
// Runs BEFORE proj so the dirty cnt/bkt lines settle into L3 during proj's ~46µs;
// epilogue then reads them via the clean L3 path (R10/R11 showed a 40µs penalty
// when the epilogue launched right after this kernel).
__global__ __launch_bounds__(256) void fill_kernel(
    const int* __restrict__ e_uu, const int* __restrict__ e_iu, const int* __restrict__ e_ui,
    int* __restrict__ cnt, int* __restrict__ bkt)
{
    int rel = blockIdx.y;
    const int* e = rel == 0 ? e_uu : (rel == 1 ? e_iu : e_ui);
    int g = blockIdx.x * 256 + threadIdx.x;
    if (g >= NEDGE) return;
    int2 sd = *(const int2*)(e + 2 * (size_t)g);
    int* c = cnt + (size_t)rel * N_USER;
    int* bk = bkt + (size_t)rel * N_USER * CAP;
    int slot = atomicAdd(&c[sd.y], 1);
    if (slot < CAP) bk[(size_t)sd.y * CAP + slot] = sd.x;
}

// Pure fused projection (R9/R10 proven config: 391 blocks, 45-48µs).
__global__ __launch_bounds__(1024, 4) void proj_kernel(
    const float* __restrict__ x_u, const float* __restrict__ x_i,
    const unsigned short* __restrict__ Wpk, const float* __restrict__ b,
    unsigned short* __restrict__ h_u, unsigned short* __restrict__ h_i)
{
    __shared__ unsigned short lds[HID * IN_DIM];  // 65536 B, packed frag order

    int tid = threadIdx.x;
    const int4* wsel = (const int4*)(Wpk + (size_t)(blockIdx.x & 7) * 32768);
    int4 w0 = wsel[tid];
    int4 w1 = wsel[1024 + tid];
    int4 w2 = wsel[2048 + tid];
    int4 w3 = wsel[3072 + tid];

    int wave = tid >> 6;
    int lane = tid & 63;
    int strip = blockIdx.x * 16 + wave;
    strip = min(strip, 2 * NSTRIP - 1);   // clamp: duplicate writes are identical
    const float* x = x_u;
    unsigned short* h = h_u;
    if (strip >= NSTRIP) { strip -= NSTRIP; x = x_i; h = h_i; }

    int row0 = strip * 16;
    int r  = lane & 15;
    int kg = lane >> 4;

    bf16x8 a[8];
    const float* xrow = x + (size_t)(row0 + r) * IN_DIM;
    #pragma unroll
    for (int kb = 0; kb < 8; ++kb) {
        float4 v0 = *(const float4*)(xrow + kb * 32 + kg * 8);
        float4 v1 = *(const float4*)(xrow + kb * 32 + kg * 8 + 4);
        unsigned int* au = (unsigned int*)&a[kb];
        au[0] = cvt_pk_bf16(v0.x, v0.y);
        au[1] = cvt_pk_bf16(v0.z, v0.w);
        au[2] = cvt_pk_bf16(v1.x, v1.y);
        au[3] = cvt_pk_bf16(v1.z, v1.w);
    }

    ((int4*)lds)[tid]        = w0;
    ((int4*)lds)[1024 + tid] = w1;
    ((int4*)lds)[2048 + tid] = w2;
    ((int4*)lds)[3072 + tid] = w3;
    __syncthreads();

    float bias[8];
    #pragma unroll
    for (int nt = 0; nt < 8; ++nt) bias[nt] = b[nt * 16 + r];

    f32x4 c[8];
    #pragma unroll
    for (int nt = 0; nt < 8; ++nt) c[nt] = (f32x4){0.f, 0.f, 0.f, 0.f};

    const bf16x8* wl = (const bf16x8*)lds + lane;
    #pragma unroll
    for (int nt = 0; nt < 8; ++nt) {
        #pragma unroll
        for (int kb = 0; kb < 8; ++kb)
            c[nt] = __builtin_amdgcn_mfma_f32_16x16x32_bf16(a[kb], wl[(nt * 8 + kb) * 64], c[nt], 0, 0, 0);
    }

    // packed store: row rr, P-positions pos = r*8+nt (col = nt*16+r), 16B per lane
    #pragma unroll
    for (int i = 0; i < 4; ++i) {
        uint4 val;
        val.x = cvt_pk_bf16(c[0][i] + bias[0], c[1][i] + bias[1]);
        val.y = cvt_pk_bf16(c[2][i] + bias[2], c[3][i] + bias[3]);
        val.z = cvt_pk_bf16(c[4][i] + bias[4], c[5][i] + bias[5]);
        val.w = cvt_pk_bf16(c[6][i] + bias[6], c[7][i] + bias[7]);
        *(uint4*)(h + (size_t)(row0 + kg * 4 + i) * HID + r * 8) = val;
    }
}

// Merged epilogue: blocks [0,3125) = fused user gather+ELU+GEMM; [3125,15625) = item gather.
__global__ __launch_bounds__(256, 4) void epilogue_kernel(
    const unsigned short* __restrict__ h_u, const unsigned short* __restrict__ h_i,
    const int* __restrict__ cnt, const int* __restrict__ bkt,
    const float* __restrict__ al_uu, const float* __restrict__ ar_uu,
    const float* __restrict__ al_iu, const float* __restrict__ ar_iu,
    const float* __restrict__ al_ui, const float* __restrict__ ar_ui,
    const unsigned short* __restrict__ Wok, const float* __restrict__ bo,
    float* __restrict__ out_u, float* __restrict__ out_i)
{
    __shared__ unsigned short gbuf[16 * HID];       // 4 KB (user path)
    __shared__ unsigned short ldsW[OUT_DIM * HID];  // 16 KB (user path)

    int tid  = threadIdx.x;
    int wave = tid >> 6;
    int lane = tid & 63;

    if (blockIdx.x >= NSTRIP) {
        // ---- item gather path ----
        int v = (blockIdx.x - NSTRIP) * 4 + wave;
        if (v >= N_ITEM) return;

        unsigned int hv = *(const unsigned int*)(h_i + (size_t)v * HID + lane * 2);

        int d = cnt[2 * N_USER + v];
        const int4* bq4 = (const int4*)(bkt + 2 * (size_t)N_USER * CAP + (size_t)v * CAP);
        int4 qa = bq4[0], qb = bq4[1];
        int idx[8] = {qa.x, qa.y, qa.z, qa.w, qb.x, qb.y, qb.z, qb.w};

        unsigned int rr[8];
        #pragma unroll
        for (int j = 0; j < 8; ++j) {
            int s = j < d ? idx[j] : v;
            rr[j] = *(const unsigned int*)(h_u + (size_t)s * HID + lane * 2);
        }
        float s0 = 0.f, s1 = 0.f;
        #pragma unroll
        for (int j = 0; j < 8; ++j) {
            float m = j < d ? 1.f : 0.f;
            s0 += m * bf2f((unsigned short)rr[j]);
            s1 += m * bf2f((unsigned short)(rr[j] >> 16));
        }
        if (d > 8) {
            int n = min(d, CAP);
            const int* bq = bkt + 2 * (size_t)N_USER * CAP + (size_t)v * CAP;
            for (int j = 8; j < n; ++j) {
                unsigned int u = *(const unsigned int*)(h_u + (size_t)bq[j] * HID + lane * 2);
                s0 += bf2f((unsigned short)u);
                s1 += bf2f((unsigned short)(u >> 16));
            }
        }

        float rscale = ar_ui[0] * (float)d;
        float o0 = elu_f(rscale * bf2f((unsigned short)hv) + al_ui[0] * s0);
        float o1 = elu_f(rscale * bf2f((unsigned short)(hv >> 16)) + al_ui[0] * s1);

        int r_pos = lane >> 2;
        int c0 = ((2 * lane) & 7) * 16 + r_pos;
        float* orow = out_i + (size_t)v * HID;
        orow[c0]      = o0;
        orow[c0 + 16] = o1;
        return;
    }

    // ---- fused user path ----
    int base = blockIdx.x * 16;

    #pragma unroll
    for (int it = 0; it < 4; ++it)
        ((int4*)ldsW)[it * 256 + tid] = ((const int4*)Wok)[it * 256 + tid];

    float aluu = al_uu[0], aruu = ar_uu[0], aliu = al_iu[0], ariu = ar_iu[0];

    #pragma unroll 1
    for (int q = 0; q < 4; ++q) {
        int vloc = wave * 4 + q;
        int v = base + vloc;

        unsigned int hv = *(const unsigned int*)(h_u + (size_t)v * HID + lane * 2);
        int d_uu = cnt[v];
        int d_iu = cnt[N_USER + v];

        const int4* b0 = (const int4*)(bkt + (size_t)v * CAP);
        const int4* b1 = (const int4*)(bkt + (size_t)N_USER * CAP + (size_t)v * CAP);
        int4 q0a = b0[0], q0b = b0[1];
        int4 q1a = b1[0], q1b = b1[1];
        int idx0[8] = {q0a.x, q0a.y, q0a.z, q0a.w, q0b.x, q0b.y, q0b.z, q0b.w};
        int idx1[8] = {q1a.x, q1a.y, q1a.z, q1a.w, q1b.x, q1b.y, q1b.z, q1b.w};

        unsigned int ru[8], ri[8];
        #pragma unroll
        for (int j = 0; j < 8; ++j) {
            int s = j < d_uu ? idx0[j] : v;
            ru[j] = *(const unsigned int*)(h_u + (size_t)s * HID + lane * 2);
        }
        #pragma unroll
        for (int j = 0; j < 8; ++j) {
            int s = j < d_iu ? idx1[j] : v;
            ri[j] = *(const unsigned int*)(h_i + (size_t)s * HID + lane * 2);
        }
        float s0u = 0.f, s1u = 0.f, s0i = 0.f, s1i = 0.f;
        #pragma unroll
        for (int j = 0; j < 8; ++j) {
            float mu = j < d_uu ? 1.f : 0.f;
            float mi = j < d_iu ? 1.f : 0.f;
            s0u += mu * bf2f((unsigned short)ru[j]);
            s1u += mu * bf2f((unsigned short)(ru[j] >> 16));
            s0i += mi * bf2f((unsigned short)ri[j]);
            s1i += mi * bf2f((unsigned short)(ri[j] >> 16));
        }
        if (d_uu > 8) {
            int n = min(d_uu, CAP);
            const int* bq = bkt + (size_t)v * CAP;
            for (int j = 8; j < n; ++j) {
                unsigned int u = *(const unsigned int*)(h_u + (size_t)bq[j] * HID + lane * 2);
                s0u += bf2f((unsigned short)u);
                s1u += bf2f((unsigned short)(u >> 16));
            }
        }
        if (d_iu > 8) {
            int n = min(d_iu, CAP);
            const int* bq = bkt + (size_t)N_USER * CAP + (size_t)v * CAP;
            for (int j = 8; j < n; ++j) {
                unsigned int u = *(const unsigned int*)(h_i + (size_t)bq[j] * HID + lane * 2);
                s0i += bf2f((unsigned short)u);
                s1i += bf2f((unsigned short)(u >> 16));
            }
        }

        float rscale = aruu * (float)d_uu + ariu * (float)d_iu;
        float acc0 = aluu * s0u + aliu * s0i + rscale * bf2f((unsigned short)hv);
        float acc1 = aluu * s1u + aliu * s1i + rscale * bf2f((unsigned short)(hv >> 16));

        unsigned int packed = cvt_pk_bf16(elu_f(acc0), elu_f(acc1));
        *(unsigned int*)((char*)gbuf + ((vloc * 256 + lane * 4) ^ ((vloc & 7) << 4))) = packed;
    }
    __syncthreads();

    if (wave == 0) {
        int r  = lane & 15;
        int kg = lane >> 4;

        bf16x8 a[4];
        #pragma unroll
        for (int kb = 0; kb < 4; ++kb)
            a[kb] = *(const bf16x8*)((const char*)gbuf +
                      (((r * 256) + kb * 64 + kg * 16) ^ ((r & 7) << 4)));

        const bf16x8* wl = (const bf16x8*)ldsW + lane;
        #pragma unroll
        for (int nt = 0; nt < 4; ++nt) {
            f32x4 c = {0.f, 0.f, 0.f, 0.f};
            #pragma unroll
            for (int kb = 0; kb < 4; ++kb)
                c = __builtin_amdgcn_mfma_f32_16x16x32_bf16(a[kb], wl[(nt * 4 + kb) * 64], c, 0, 0, 0);
            float bias = bo[nt * 16 + r];
            #pragma unroll
            for (int i = 0; i < 4; ++i)
                out_u[(size_t)(base + kg * 4 + i) * OUT_DIM + nt * 16 + r] = c[i] + bias;
        }
    }
}

extern "C" void kernel_launch(void* const* d_in, const int* in_sizes, int n_in,
                              void* d_out, int out_size, void* d_ws, size_t ws_size,
                              hipStream_t stream)
{
    const float* x_user = (const float*)d_in[0];
    const float* x_item = (const float*)d_in[1];
    const float* W_proj = (const float*)d_in[2];
    const float* b_proj = (const float*)d_in[3];
    const float* al_uu  = (const float*)d_in[4];
    const float* ar_uu  = (const float*)d_in[5];
    const float* al_iu  = (const float*)d_in[6];
    const float* ar_iu  = (const float*)d_in[7];
    const float* al_ui  = (const float*)d_in[8];
    const float* ar_ui  = (const float*)d_in[9];
    const float* W_out  = (const float*)d_in[10];
    const float* b_out  = (const float*)d_in[11];
    const int* edges_uu = (const int*)d_in[12];
    const int* edges_iu = (const int*)d_in[13];
    const int* edges_ui = (const int*)d_in[14];

    char* ws = (char*)d_ws;
    unsigned short* h_u = (unsigned short*)(ws);                   // 12,800,000
    unsigned short* h_i = (unsigned short*)(ws + 12800000);        // 12,800,000
    unsigned short* Wpk = (unsigned short*)(ws + 25600000);        //    524,288 (8 copies)
    unsigned short* Wok = (unsigned short*)(ws + 26124288);        //     16,384
    int* cnt            = (int*)(ws + 26140672);                   //    600,000 (3 x 50000)
    int* bkt            = (int*)(ws + 26740672);                   // 19,200,000 (3 x 50000 x 32)

    float* out_u = (float*)d_out;
    float* out_i = out_u + (size_t)N_USER * OUT_DIM;

    dim3 blk(256);
    // pack W (blocks 0..19) + zero cnt (blocks 20..605)
    pack_w_kernel<<<dim3(606), blk, 0, stream>>>(W_proj, W_out, Wpk, Wok, cnt);

    // fill FIRST: dirty cnt/bkt lines settle into L3 during proj's ~46µs
    fill_kernel<<<dim3(782, 3), blk, 0, stream>>>(edges_uu, edges_iu, edges_ui, cnt, bkt);

    proj_kernel<<<dim3(PROJ_GRID), dim3(1024), 0, stream>>>(x_user, x_item, Wpk, b_proj, h_u, h_i);

    epilogue_kernel<<<dim3(NSTRIP + 12500), blk, 0, stream>>>(
        h_u, h_i, cnt, bkt, al_uu, ar_uu, al_iu, ar_iu, al_ui, ar_ui,
        Wok, b_out, out_u, out_i);
}

// Round 15
// 93.200 us; speedup vs baseline: 1.1714x; 1.1714x over previous
//
#include <hip/hip_runtime.h>
#include <hip/hip_bf16.h>

typedef short bf16x8 __attribute__((ext_vector_type(8)));
typedef float f32x4 __attribute__((ext_vector_type(4)));

#define N_USER 50000
#define N_ITEM 50000
#define IN_DIM 256
#define HID 128
#define OUT_DIM 64
#define NEDGE 200000
#define CAP 32
#define NSTRIP 3125    // 50000/16
#define FILL_GRID 64   // grid-stride fill blocks inside the proj dispatch (R13 config)
#define PROJ_GRID 391  // ceil(6250 strips / 16 waves)

__device__ __forceinline__ float bf2f(unsigned short u) {
    union { unsigned int i; float f; } v; v.i = ((unsigned int)u) << 16; return v.f;
}
__device__ __forceinline__ unsigned short f2bf(float f) {
    union { float f; unsigned int i; } v; v.f = f;
    return (unsigned short)((v.i + 0x7fffu + ((v.i >> 16) & 1u)) >> 16);
}
__device__ __forceinline__ unsigned int cvt_pk_bf16(float a, float b) {
    unsigned int r;
    asm("v_cvt_pk_bf16_f32 %0, %1, %2" : "=v"(r) : "v"(a), "v"(b));
    return r;
}
__device__ __forceinline__ float elu_f(float x) {
    return x > 0.f ? x : (__expf(x) - 1.f);
}

// ---- pack weights (frag order) + zero cnt, one launch ----
__global__ __launch_bounds__(256) void pack_w_kernel(
    const float* __restrict__ Wp, const float* __restrict__ Wo,
    unsigned short* __restrict__ Wpk, unsigned short* __restrict__ Wok,
    int* __restrict__ cnt)
{
    int bid = blockIdx.x;
    if (bid >= 20) {
        int idx = (bid - 20) * 256 + threadIdx.x;
        if (idx < 3 * N_USER) cnt[idx] = 0;
        return;
    }
    int t = bid * 256 + threadIdx.x;
    if (t < 4096) {
        int lane = t & 63, kb = (t >> 6) & 7, nt = t >> 9;
        int r = lane & 15, kg = lane >> 4;
        unsigned short o[8];
        #pragma unroll
        for (int j = 0; j < 8; ++j)
            o[j] = f2bf(Wp[(size_t)(kb * 32 + kg * 8 + j) * HID + nt * 16 + r]);
        for (int cp = 0; cp < 8; ++cp) {
            #pragma unroll
            for (int j = 0; j < 8; ++j) Wpk[cp * 32768 + t * 8 + j] = o[j];
        }
    } else if (t < 4096 + 1024) {
        int q = t - 4096;
        int lane = q & 63, kb = (q >> 6) & 3, nt = q >> 8;
        int r = lane & 15, kg = lane >> 4;
        unsigned short o[8];
        #pragma unroll
        for (int j = 0; j < 8; ++j)
            o[j] = f2bf(Wo[(size_t)(j * 16 + kb * 4 + kg) * OUT_DIM + nt * 16 + r]);
        #pragma unroll
        for (int j = 0; j < 8; ++j) Wok[q * 8 + j] = o[j];
    }
}

// Blocks [0,64): grid-stride edge bucket-fill. Blocks [64,455): fused projection.
// R13 config — best measured total (93.8µs). Fill-inside-this-dispatch keeps the
// epilogue fast (standalone fill costs the epilogue ~40µs; see R11/R14 vs R12/R13).
__global__ __launch_bounds__(1024, 4) void proj_kernel(
    const float* __restrict__ x_u, const float* __restrict__ x_i,
    const unsigned short* __restrict__ Wpk, const float* __restrict__ b,
    unsigned short* __restrict__ h_u, unsigned short* __restrict__ h_i,
    const int* __restrict__ e_uu, const int* __restrict__ e_iu,
    const int* __restrict__ e_ui, int* __restrict__ cnt, int* __restrict__ bkt)
{
    __shared__ unsigned short lds[HID * IN_DIM];  // 65536 B, packed frag order

    int tid = threadIdx.x;
    int bid = blockIdx.x;

    if (bid < FILL_GRID) {
        for (int g = bid * 1024 + tid; g < 3 * NEDGE; g += FILL_GRID * 1024) {
            int rel = g >= 2 * NEDGE ? 2 : (g >= NEDGE ? 1 : 0);
            const int* e = rel == 0 ? e_uu : (rel == 1 ? e_iu : e_ui);
            int eid = g - rel * NEDGE;
            int2 sd = *(const int2*)(e + 2 * (size_t)eid);
            int* c  = cnt + (size_t)rel * N_USER;
            int* bk = bkt + (size_t)rel * N_USER * CAP;
            int slot = atomicAdd(&c[sd.y], 1);
            if (slot < CAP) bk[(size_t)sd.y * CAP + slot] = sd.x;
        }
        return;
    }
    bid -= FILL_GRID;

    // ---- projection path ----
    const int4* wsel = (const int4*)(Wpk + (size_t)(bid & 7) * 32768);
    int4 w0 = wsel[tid];
    int4 w1 = wsel[1024 + tid];
    int4 w2 = wsel[2048 + tid];
    int4 w3 = wsel[3072 + tid];

    int wave = tid >> 6;
    int lane = tid & 63;
    int strip = bid * 16 + wave;
    strip = min(strip, 2 * NSTRIP - 1);   // clamp: duplicate writes are identical
    const float* x = x_u;
    unsigned short* h = h_u;
    if (strip >= NSTRIP) { strip -= NSTRIP; x = x_i; h = h_i; }

    int row0 = strip * 16;
    int r  = lane & 15;
    int kg = lane >> 4;

    bf16x8 a[8];
    const float* xrow = x + (size_t)(row0 + r) * IN_DIM;
    #pragma unroll
    for (int kb = 0; kb < 8; ++kb) {
        float4 v0 = *(const float4*)(xrow + kb * 32 + kg * 8);
        float4 v1 = *(const float4*)(xrow + kb * 32 + kg * 8 + 4);
        unsigned int* au = (unsigned int*)&a[kb];
        au[0] = cvt_pk_bf16(v0.x, v0.y);
        au[1] = cvt_pk_bf16(v0.z, v0.w);
        au[2] = cvt_pk_bf16(v1.x, v1.y);
        au[3] = cvt_pk_bf16(v1.z, v1.w);
    }

    ((int4*)lds)[tid]        = w0;
    ((int4*)lds)[1024 + tid] = w1;
    ((int4*)lds)[2048 + tid] = w2;
    ((int4*)lds)[3072 + tid] = w3;
    __syncthreads();

    float bias[8];
    #pragma unroll
    for (int nt = 0; nt < 8; ++nt) bias[nt] = b[nt * 16 + r];

    f32x4 c[8];
    #pragma unroll
    for (int nt = 0; nt < 8; ++nt) c[nt] = (f32x4){0.f, 0.f, 0.f, 0.f};

    const bf16x8* wl = (const bf16x8*)lds + lane;
    #pragma unroll
    for (int nt = 0; nt < 8; ++nt) {
        #pragma unroll
        for (int kb = 0; kb < 8; ++kb)
            c[nt] = __builtin_amdgcn_mfma_f32_16x16x32_bf16(a[kb], wl[(nt * 8 + kb) * 64], c[nt], 0, 0, 0);
    }

    // packed store: row rr, P-positions pos = r*8+nt (col = nt*16+r), 16B per lane
    #pragma unroll
    for (int i = 0; i < 4; ++i) {
        uint4 val;
        val.x = cvt_pk_bf16(c[0][i] + bias[0], c[1][i] + bias[1]);
        val.y = cvt_pk_bf16(c[2][i] + bias[2], c[3][i] + bias[3]);
        val.z = cvt_pk_bf16(c[4][i] + bias[4], c[5][i] + bias[5]);
        val.w = cvt_pk_bf16(c[6][i] + bias[6], c[7][i] + bias[7]);
        *(uint4*)(h + (size_t)(row0 + kg * 4 + i) * HID + r * 8) = val;
    }
}

// Merged epilogue: blocks [0,3125) = fused user gather+ELU+GEMM; [3125,15625) = item gather.
// VALU cut: unmasked sums + subtract-self-overcount correction (slot 7 is guaranteed
// to hold the fallback value whenever n < 8; the correction multiplier is 0 at n == 8).
__global__ __launch_bounds__(256, 4) void epilogue_kernel(
    const unsigned short* __restrict__ h_u, const unsigned short* __restrict__ h_i,
    const int* __restrict__ cnt, const int* __restrict__ bkt,
    const float* __restrict__ al_uu, const float* __restrict__ ar_uu,
    const float* __restrict__ al_iu, const float* __restrict__ ar_iu,
    const float* __restrict__ al_ui, const float* __restrict__ ar_ui,
    const unsigned short* __restrict__ Wok, const float* __restrict__ bo,
    float* __restrict__ out_u, float* __restrict__ out_i)
{
    __shared__ unsigned short gbuf[16 * HID];       // 4 KB (user path)
    __shared__ unsigned short ldsW[OUT_DIM * HID];  // 16 KB (user path)

    int tid  = threadIdx.x;
    int wave = tid >> 6;
    int lane = tid & 63;

    if (blockIdx.x >= NSTRIP) {
        // ---- item gather path ----
        int v = (blockIdx.x - NSTRIP) * 4 + wave;
        if (v >= N_ITEM) return;

        unsigned int hv = *(const unsigned int*)(h_i + (size_t)v * HID + lane * 2);

        int d = cnt[2 * N_USER + v];
        const int4* bq4 = (const int4*)(bkt + 2 * (size_t)N_USER * CAP + (size_t)v * CAP);
        int4 qa = bq4[0], qb = bq4[1];
        int idx[8] = {qa.x, qa.y, qa.z, qa.w, qb.x, qb.y, qb.z, qb.w};

        unsigned int rr[8];
        #pragma unroll
        for (int j = 0; j < 8; ++j) {
            int s = j < d ? idx[j] : v;
            rr[j] = *(const unsigned int*)(h_u + (size_t)s * HID + lane * 2);
        }
        float s0 = 0.f, s1 = 0.f;
        #pragma unroll
        for (int j = 0; j < 8; ++j) {
            s0 += bf2f((unsigned short)rr[j]);
            s1 += bf2f((unsigned short)(rr[j] >> 16));
        }
        // subtract over-counted fallback (h_u[v], present in slot 7 whenever n<8)
        int n = min(d, 8);
        float over = (float)(8 - n);
        s0 -= over * bf2f((unsigned short)rr[7]);
        s1 -= over * bf2f((unsigned short)(rr[7] >> 16));
        if (d > 8) {
            int nn = min(d, CAP);
            const int* bq = bkt + 2 * (size_t)N_USER * CAP + (size_t)v * CAP;
            for (int j = 8; j < nn; ++j) {
                unsigned int u = *(const unsigned int*)(h_u + (size_t)bq[j] * HID + lane * 2);
                s0 += bf2f((unsigned short)u);
                s1 += bf2f((unsigned short)(u >> 16));
            }
        }

        float rscale = ar_ui[0] * (float)d;
        float o0 = elu_f(rscale * bf2f((unsigned short)hv) + al_ui[0] * s0);
        float o1 = elu_f(rscale * bf2f((unsigned short)(hv >> 16)) + al_ui[0] * s1);

        int r_pos = lane >> 2;
        int c0 = ((2 * lane) & 7) * 16 + r_pos;
        float* orow = out_i + (size_t)v * HID;
        orow[c0]      = o0;
        orow[c0 + 16] = o1;
        return;
    }

    // ---- fused user path ----
    int base = blockIdx.x * 16;

    #pragma unroll
    for (int it = 0; it < 4; ++it)
        ((int4*)ldsW)[it * 256 + tid] = ((const int4*)Wok)[it * 256 + tid];

    float aluu = al_uu[0], aruu = ar_uu[0], aliu = al_iu[0], ariu = ar_iu[0];

    #pragma unroll 1
    for (int q = 0; q < 4; ++q) {
        int vloc = wave * 4 + q;
        int v = base + vloc;

        unsigned int hv = *(const unsigned int*)(h_u + (size_t)v * HID + lane * 2);
        int d_uu = cnt[v];
        int d_iu = cnt[N_USER + v];

        const int4* b0 = (const int4*)(bkt + (size_t)v * CAP);
        const int4* b1 = (const int4*)(bkt + (size_t)N_USER * CAP + (size_t)v * CAP);
        int4 q0a = b0[0], q0b = b0[1];
        int4 q1a = b1[0], q1b = b1[1];
        int idx0[8] = {q0a.x, q0a.y, q0a.z, q0a.w, q0b.x, q0b.y, q0b.z, q0b.w};
        int idx1[8] = {q1a.x, q1a.y, q1a.z, q1a.w, q1b.x, q1b.y, q1b.z, q1b.w};

        unsigned int ru[8], ri[8];
        #pragma unroll
        for (int j = 0; j < 8; ++j) {
            int s = j < d_uu ? idx0[j] : v;
            ru[j] = *(const unsigned int*)(h_u + (size_t)s * HID + lane * 2);
        }
        #pragma unroll
        for (int j = 0; j < 8; ++j) {
            int s = j < d_iu ? idx1[j] : v;
            ri[j] = *(const unsigned int*)(h_i + (size_t)s * HID + lane * 2);
        }
        float s0u = 0.f, s1u = 0.f, s0i = 0.f, s1i = 0.f;
        #pragma unroll
        for (int j = 0; j < 8; ++j) {
            s0u += bf2f((unsigned short)ru[j]);
            s1u += bf2f((unsigned short)(ru[j] >> 16));
            s0i += bf2f((unsigned short)ri[j]);
            s1i += bf2f((unsigned short)(ri[j] >> 16));
        }
        // subtract over-counted fallbacks (user fallback = h_u[v]; item-side = h_i[v];
        // both present in slot 7 whenever the respective n < 8)
        int nu = min(d_uu, 8), ni = min(d_iu, 8);
        float ovu = (float)(8 - nu), ovi = (float)(8 - ni);
        s0u -= ovu * bf2f((unsigned short)ru[7]);
        s1u -= ovu * bf2f((unsigned short)(ru[7] >> 16));
        s0i -= ovi * bf2f((unsigned short)ri[7]);
        s1i -= ovi * bf2f((unsigned short)(ri[7] >> 16));
        if (d_uu > 8) {
            int nn = min(d_uu, CAP);
            const int* bq = bkt + (size_t)v * CAP;
            for (int j = 8; j < nn; ++j) {
                unsigned int u = *(const unsigned int*)(h_u + (size_t)bq[j] * HID + lane * 2);
                s0u += bf2f((unsigned short)u);
                s1u += bf2f((unsigned short)(u >> 16));
            }
        }
        if (d_iu > 8) {
            int nn = min(d_iu, CAP);
            const int* bq = bkt + (size_t)N_USER * CAP + (size_t)v * CAP;
            for (int j = 8; j < nn; ++j) {
                unsigned int u = *(const unsigned int*)(h_i + (size_t)bq[j] * HID + lane * 2);
                s0i += bf2f((unsigned short)u);
                s1i += bf2f((unsigned short)(u >> 16));
            }
        }

        float rscale = aruu * (float)d_uu + ariu * (float)d_iu;
        float acc0 = aluu * s0u + aliu * s0i + rscale * bf2f((unsigned short)hv);
        float acc1 = aluu * s1u + aliu * s1i + rscale * bf2f((unsigned short)(hv >> 16));

        unsigned int packed = cvt_pk_bf16(elu_f(acc0), elu_f(acc1));
        *(unsigned int*)((char*)gbuf + ((vloc * 256 + lane * 4) ^ ((vloc & 7) << 4))) = packed;
    }
    __syncthreads();

    if (wave == 0) {
        int r  = lane & 15;
        int kg = lane >> 4;

        bf16x8 a[4];
        #pragma unroll
        for (int kb = 0; kb < 4; ++kb)
            a[kb] = *(const bf16x8*)((const char*)gbuf +
                      (((r * 256) + kb * 64 + kg * 16) ^ ((r & 7) << 4)));

        const bf16x8* wl = (const bf16x8*)ldsW + lane;
        #pragma unroll
        for (int nt = 0; nt < 4; ++nt) {
            f32x4 c = {0.f, 0.f, 0.f, 0.f};
            #pragma unroll
            for (int kb = 0; kb < 4; ++kb)
                c = __builtin_amdgcn_mfma_f32_16x16x32_bf16(a[kb], wl[(nt * 4 + kb) * 64], c, 0, 0, 0);
            float bias = bo[nt * 16 + r];
            #pragma unroll
            for (int i = 0; i < 4; ++i)
                out_u[(size_t)(base + kg * 4 + i) * OUT_DIM + nt * 16 + r] = c[i] + bias;
        }
    }
}

extern "C" void kernel_launch(void* const* d_in, const int* in_sizes, int n_in,
                              void* d_out, int out_size, void* d_ws, size_t ws_size,
                              hipStream_t stream)
{
    const float* x_user = (const float*)d_in[0];
    const float* x_item = (const float*)d_in[1];
    const float* W_proj = (const float*)d_in[2];
    const float* b_proj = (const float*)d_in[3];
    const float* al_uu  = (const float*)d_in[4];
    const float* ar_uu  = (const float*)d_in[5];
    const float* al_iu  = (const float*)d_in[6];
    const float* ar_iu  = (const float*)d_in[7];
    const float* al_ui  = (const float*)d_in[8];
    const float* ar_ui  = (const float*)d_in[9];
    const float* W_out  = (const float*)d_in[10];
    const float* b_out  = (const float*)d_in[11];
    const int* edges_uu = (const int*)d_in[12];
    const int* edges_iu = (const int*)d_in[13];
    const int* edges_ui = (const int*)d_in[14];

    char* ws = (char*)d_ws;
    unsigned short* h_u = (unsigned short*)(ws);                   // 12,800,000
    unsigned short* h_i = (unsigned short*)(ws + 12800000);        // 12,800,000
    unsigned short* Wpk = (unsigned short*)(ws + 25600000);        //    524,288 (8 copies)
    unsigned short* Wok = (unsigned short*)(ws + 26124288);        //     16,384
    int* cnt            = (int*)(ws + 26140672);                   //    600,000 (3 x 50000)
    int* bkt            = (int*)(ws + 26740672);                   // 19,200,000 (3 x 50000 x 32)

    float* out_u = (float*)d_out;
    float* out_i = out_u + (size_t)N_USER * OUT_DIM;

    dim3 blk(256);
    // pack W (blocks 0..19) + zero cnt (blocks 20..605)
    pack_w_kernel<<<dim3(606), blk, 0, stream>>>(W_proj, W_out, Wpk, Wok, cnt);

    // fill (blocks 0..63, grid-stride) + proj (blocks 64..454) in one dispatch (R13)
    proj_kernel<<<dim3(FILL_GRID + PROJ_GRID), dim3(1024), 0, stream>>>(
        x_user, x_item, Wpk, b_proj, h_u, h_i,
        edges_uu, edges_iu, edges_ui, cnt, bkt);

    epilogue_kernel<<<dim3(NSTRIP + 12500), blk, 0, stream>>>(
        h_u, h_i, cnt, bkt, al_uu, ar_uu, al_iu, ar_iu, al_ui, ar_ui,
        Wok, b_out, out_u, out_i);
}

// Round 16
// 85.687 us; speedup vs baseline: 1.2741x; 1.0877x over previous
//
#include <hip/hip_runtime.h>
#include <hip/hip_bf16.h>

typedef short bf16x8 __attribute__((ext_vector_type(8)));
typedef float f32x4 __attribute__((ext_vector_type(4)));

#define N_USER 50000
#define N_ITEM 50000
#define IN_DIM 256
#define HID 128
#define OUT_DIM 64
#define NEDGE 200000
#define CAP 32
#define NSTRIP 3125    // 50000/16
#define FILL_GRID 121  // grid-stride fill blocks; 121+391 = 512 = exactly 2 blocks/CU
#define PROJ_GRID 391  // ceil(6250 strips / 16 waves)

__device__ __forceinline__ float bf2f(unsigned short u) {
    union { unsigned int i; float f; } v; v.i = ((unsigned int)u) << 16; return v.f;
}
__device__ __forceinline__ unsigned short f2bf(float f) {
    union { float f; unsigned int i; } v; v.f = f;
    return (unsigned short)((v.i + 0x7fffu + ((v.i >> 16) & 1u)) >> 16);
}
__device__ __forceinline__ unsigned int cvt_pk_bf16(float a, float b) {
    unsigned int r;
    asm("v_cvt_pk_bf16_f32 %0, %1, %2" : "=v"(r) : "v"(a), "v"(b));
    return r;
}
__device__ __forceinline__ float elu_f(float x) {
    return x > 0.f ? x : (__expf(x) - 1.f);
}

// ---- pack weights (frag order) + zero cnt, one launch ----
__global__ __launch_bounds__(256) void pack_w_kernel(
    const float* __restrict__ Wp, const float* __restrict__ Wo,
    unsigned short* __restrict__ Wpk, unsigned short* __restrict__ Wok,
    int* __restrict__ cnt)
{
    int bid = blockIdx.x;
    if (bid >= 20) {
        int idx = (bid - 20) * 256 + threadIdx.x;
        if (idx < 3 * N_USER) cnt[idx] = 0;
        return;
    }
    int t = bid * 256 + threadIdx.x;
    if (t < 4096) {
        int lane = t & 63, kb = (t >> 6) & 7, nt = t >> 9;
        int r = lane & 15, kg = lane >> 4;
        unsigned short o[8];
        #pragma unroll
        for (int j = 0; j < 8; ++j)
            o[j] = f2bf(Wp[(size_t)(kb * 32 + kg * 8 + j) * HID + nt * 16 + r]);
        for (int cp = 0; cp < 8; ++cp) {
            #pragma unroll
            for (int j = 0; j < 8; ++j) Wpk[cp * 32768 + t * 8 + j] = o[j];
        }
    } else if (t < 4096 + 1024) {
        int q = t - 4096;
        int lane = q & 63, kb = (q >> 6) & 3, nt = q >> 8;
        int r = lane & 15, kg = lane >> 4;
        unsigned short o[8];
        #pragma unroll
        for (int j = 0; j < 8; ++j)
            o[j] = f2bf(Wo[(size_t)(j * 16 + kb * 4 + kg) * OUT_DIM + nt * 16 + r]);
        #pragma unroll
        for (int j = 0; j < 8; ++j) Wok[q * 8 + j] = o[j];
    }
}

// Blocks [0,121): grid-stride edge bucket-fill into split hot/cold buckets.
// Blocks [121,512): fused projection. All 512 blocks co-resident (2/CU).
// bkt8 (slots 0-7, 32B/dst): 97.9% of edges; 4 dsts/128B-line -> 4x less
// write-allocate line traffic than the old CAP=32 (128B/dst) layout.
// bktx (slots 8-31): ~1.6k edges/relation, negligible traffic.
__global__ __launch_bounds__(1024, 4) void proj_kernel(
    const float* __restrict__ x_u, const float* __restrict__ x_i,
    const unsigned short* __restrict__ Wpk, const float* __restrict__ b,
    unsigned short* __restrict__ h_u, unsigned short* __restrict__ h_i,
    const int* __restrict__ e_uu, const int* __restrict__ e_iu,
    const int* __restrict__ e_ui, int* __restrict__ cnt,
    int* __restrict__ bkt8, int* __restrict__ bktx)
{
    __shared__ unsigned short lds[HID * IN_DIM];  // 65536 B, packed frag order

    int tid = threadIdx.x;
    int bid = blockIdx.x;

    if (bid < FILL_GRID) {
        for (int g = bid * 1024 + tid; g < 3 * NEDGE; g += FILL_GRID * 1024) {
            int rel = g >= 2 * NEDGE ? 2 : (g >= NEDGE ? 1 : 0);
            const int* e = rel == 0 ? e_uu : (rel == 1 ? e_iu : e_ui);
            int eid = g - rel * NEDGE;
            int2 sd = *(const int2*)(e + 2 * (size_t)eid);
            size_t drow = (size_t)rel * N_USER + sd.y;
            int slot = atomicAdd(&cnt[drow], 1);
            if (slot < 8)        bkt8[drow * 8 + slot] = sd.x;
            else if (slot < CAP) bktx[drow * 24 + (slot - 8)] = sd.x;
        }
        return;
    }
    bid -= FILL_GRID;

    // ---- projection path ----
    const int4* wsel = (const int4*)(Wpk + (size_t)(bid & 7) * 32768);
    int4 w0 = wsel[tid];
    int4 w1 = wsel[1024 + tid];
    int4 w2 = wsel[2048 + tid];
    int4 w3 = wsel[3072 + tid];

    int wave = tid >> 6;
    int lane = tid & 63;
    int strip = bid * 16 + wave;
    strip = min(strip, 2 * NSTRIP - 1);   // clamp: duplicate writes are identical
    const float* x = x_u;
    unsigned short* h = h_u;
    if (strip >= NSTRIP) { strip -= NSTRIP; x = x_i; h = h_i; }

    int row0 = strip * 16;
    int r  = lane & 15;
    int kg = lane >> 4;

    bf16x8 a[8];
    const float* xrow = x + (size_t)(row0 + r) * IN_DIM;
    #pragma unroll
    for (int kb = 0; kb < 8; ++kb) {
        float4 v0 = *(const float4*)(xrow + kb * 32 + kg * 8);
        float4 v1 = *(const float4*)(xrow + kb * 32 + kg * 8 + 4);
        unsigned int* au = (unsigned int*)&a[kb];
        au[0] = cvt_pk_bf16(v0.x, v0.y);
        au[1] = cvt_pk_bf16(v0.z, v0.w);
        au[2] = cvt_pk_bf16(v1.x, v1.y);
        au[3] = cvt_pk_bf16(v1.z, v1.w);
    }

    ((int4*)lds)[tid]        = w0;
    ((int4*)lds)[1024 + tid] = w1;
    ((int4*)lds)[2048 + tid] = w2;
    ((int4*)lds)[3072 + tid] = w3;
    __syncthreads();

    float bias[8];
    #pragma unroll
    for (int nt = 0; nt < 8; ++nt) bias[nt] = b[nt * 16 + r];

    f32x4 c[8];
    #pragma unroll
    for (int nt = 0; nt < 8; ++nt) c[nt] = (f32x4){0.f, 0.f, 0.f, 0.f};

    const bf16x8* wl = (const bf16x8*)lds + lane;
    #pragma unroll
    for (int nt = 0; nt < 8; ++nt) {
        #pragma unroll
        for (int kb = 0; kb < 8; ++kb)
            c[nt] = __builtin_amdgcn_mfma_f32_16x16x32_bf16(a[kb], wl[(nt * 8 + kb) * 64], c[nt], 0, 0, 0);
    }

    // packed store: row rr, P-positions pos = r*8+nt (col = nt*16+r), 16B per lane
    #pragma unroll
    for (int i = 0; i < 4; ++i) {
        uint4 val;
        val.x = cvt_pk_bf16(c[0][i] + bias[0], c[1][i] + bias[1]);
        val.y = cvt_pk_bf16(c[2][i] + bias[2], c[3][i] + bias[3]);
        val.z = cvt_pk_bf16(c[4][i] + bias[4], c[5][i] + bias[5]);
        val.w = cvt_pk_bf16(c[6][i] + bias[6], c[7][i] + bias[7]);
        *(uint4*)(h + (size_t)(row0 + kg * 4 + i) * HID + r * 8) = val;
    }
}

// Merged epilogue: blocks [0,3125) = fused user gather+ELU+GEMM; [3125,15625) = item gather.
// Unmasked sums + subtract-self-overcount correction (slot 7 holds the fallback when n<8).
__global__ __launch_bounds__(256, 4) void epilogue_kernel(
    const unsigned short* __restrict__ h_u, const unsigned short* __restrict__ h_i,
    const int* __restrict__ cnt, const int* __restrict__ bkt8, const int* __restrict__ bktx,
    const float* __restrict__ al_uu, const float* __restrict__ ar_uu,
    const float* __restrict__ al_iu, const float* __restrict__ ar_iu,
    const float* __restrict__ al_ui, const float* __restrict__ ar_ui,
    const unsigned short* __restrict__ Wok, const float* __restrict__ bo,
    float* __restrict__ out_u, float* __restrict__ out_i)
{
    __shared__ unsigned short gbuf[16 * HID];       // 4 KB (user path)
    __shared__ unsigned short ldsW[OUT_DIM * HID];  // 16 KB (user path)

    int tid  = threadIdx.x;
    int wave = tid >> 6;
    int lane = tid & 63;

    if (blockIdx.x >= NSTRIP) {
        // ---- item gather path ----
        int v = (blockIdx.x - NSTRIP) * 4 + wave;
        if (v >= N_ITEM) return;

        unsigned int hv = *(const unsigned int*)(h_i + (size_t)v * HID + lane * 2);

        int d = cnt[2 * N_USER + v];
        const int4* bq4 = (const int4*)(bkt8 + (2 * (size_t)N_USER + v) * 8);
        int4 qa = bq4[0], qb = bq4[1];
        int idx[8] = {qa.x, qa.y, qa.z, qa.w, qb.x, qb.y, qb.z, qb.w};

        unsigned int rr[8];
        #pragma unroll
        for (int j = 0; j < 8; ++j) {
            int s = j < d ? idx[j] : v;
            rr[j] = *(const unsigned int*)(h_u + (size_t)s * HID + lane * 2);
        }
        float s0 = 0.f, s1 = 0.f;
        #pragma unroll
        for (int j = 0; j < 8; ++j) {
            s0 += bf2f((unsigned short)rr[j]);
            s1 += bf2f((unsigned short)(rr[j] >> 16));
        }
        int n = min(d, 8);
        float over = (float)(8 - n);
        s0 -= over * bf2f((unsigned short)rr[7]);
        s1 -= over * bf2f((unsigned short)(rr[7] >> 16));
        if (d > 8) {
            int nn = min(d, CAP);
            const int* bq = bktx + (2 * (size_t)N_USER + v) * 24;
            for (int j = 8; j < nn; ++j) {
                unsigned int u = *(const unsigned int*)(h_u + (size_t)bq[j - 8] * HID + lane * 2);
                s0 += bf2f((unsigned short)u);
                s1 += bf2f((unsigned short)(u >> 16));
            }
        }

        float rscale = ar_ui[0] * (float)d;
        float o0 = elu_f(rscale * bf2f((unsigned short)hv) + al_ui[0] * s0);
        float o1 = elu_f(rscale * bf2f((unsigned short)(hv >> 16)) + al_ui[0] * s1);

        int r_pos = lane >> 2;
        int c0 = ((2 * lane) & 7) * 16 + r_pos;
        float* orow = out_i + (size_t)v * HID;
        orow[c0]      = o0;
        orow[c0 + 16] = o1;
        return;
    }

    // ---- fused user path ----
    int base = blockIdx.x * 16;

    #pragma unroll
    for (int it = 0; it < 4; ++it)
        ((int4*)ldsW)[it * 256 + tid] = ((const int4*)Wok)[it * 256 + tid];

    float aluu = al_uu[0], aruu = ar_uu[0], aliu = al_iu[0], ariu = ar_iu[0];

    #pragma unroll 1
    for (int q = 0; q < 4; ++q) {
        int vloc = wave * 4 + q;
        int v = base + vloc;

        unsigned int hv = *(const unsigned int*)(h_u + (size_t)v * HID + lane * 2);
        int d_uu = cnt[v];
        int d_iu = cnt[N_USER + v];

        const int4* b0 = (const int4*)(bkt8 + (size_t)v * 8);
        const int4* b1 = (const int4*)(bkt8 + ((size_t)N_USER + v) * 8);
        int4 q0a = b0[0], q0b = b0[1];
        int4 q1a = b1[0], q1b = b1[1];
        int idx0[8] = {q0a.x, q0a.y, q0a.z, q0a.w, q0b.x, q0b.y, q0b.z, q0b.w};
        int idx1[8] = {q1a.x, q1a.y, q1a.z, q1a.w, q1b.x, q1b.y, q1b.z, q1b.w};

        unsigned int ru[8], ri[8];
        #pragma unroll
        for (int j = 0; j < 8; ++j) {
            int s = j < d_uu ? idx0[j] : v;
            ru[j] = *(const unsigned int*)(h_u + (size_t)s * HID + lane * 2);
        }
        #pragma unroll
        for (int j = 0; j < 8; ++j) {
            int s = j < d_iu ? idx1[j] : v;
            ri[j] = *(const unsigned int*)(h_i + (size_t)s * HID + lane * 2);
        }
        float s0u = 0.f, s1u = 0.f, s0i = 0.f, s1i = 0.f;
        #pragma unroll
        for (int j = 0; j < 8; ++j) {
            s0u += bf2f((unsigned short)ru[j]);
            s1u += bf2f((unsigned short)(ru[j] >> 16));
            s0i += bf2f((unsigned short)ri[j]);
            s1i += bf2f((unsigned short)(ri[j] >> 16));
        }
        int nu = min(d_uu, 8), ni = min(d_iu, 8);
        float ovu = (float)(8 - nu), ovi = (float)(8 - ni);
        s0u -= ovu * bf2f((unsigned short)ru[7]);
        s1u -= ovu * bf2f((unsigned short)(ru[7] >> 16));
        s0i -= ovi * bf2f((unsigned short)ri[7]);
        s1i -= ovi * bf2f((unsigned short)(ri[7] >> 16));
        if (d_uu > 8) {
            int nn = min(d_uu, CAP);
            const int* bq = bktx + (size_t)v * 24;
            for (int j = 8; j < nn; ++j) {
                unsigned int u = *(const unsigned int*)(h_u + (size_t)bq[j - 8] * HID + lane * 2);
                s0u += bf2f((unsigned short)u);
                s1u += bf2f((unsigned short)(u >> 16));
            }
        }
        if (d_iu > 8) {
            int nn = min(d_iu, CAP);
            const int* bq = bktx + ((size_t)N_USER + v) * 24;
            for (int j = 8; j < nn; ++j) {
                unsigned int u = *(const unsigned int*)(h_i + (size_t)bq[j - 8] * HID + lane * 2);
                s0i += bf2f((unsigned short)u);
                s1i += bf2f((unsigned short)(u >> 16));
            }
        }

        float rscale = aruu * (float)d_uu + ariu * (float)d_iu;
        float acc0 = aluu * s0u + aliu * s0i + rscale * bf2f((unsigned short)hv);
        float acc1 = aluu * s1u + aliu * s1i + rscale * bf2f((unsigned short)(hv >> 16));

        unsigned int packed = cvt_pk_bf16(elu_f(acc0), elu_f(acc1));
        *(unsigned int*)((char*)gbuf + ((vloc * 256 + lane * 4) ^ ((vloc & 7) << 4))) = packed;
    }
    __syncthreads();

    if (wave == 0) {
        int r  = lane & 15;
        int kg = lane >> 4;

        bf16x8 a[4];
        #pragma unroll
        for (int kb = 0; kb < 4; ++kb)
            a[kb] = *(const bf16x8*)((const char*)gbuf +
                      (((r * 256) + kb * 64 + kg * 16) ^ ((r & 7) << 4)));

        const bf16x8* wl = (const bf16x8*)ldsW + lane;
        #pragma unroll
        for (int nt = 0; nt < 4; ++nt) {
            f32x4 c = {0.f, 0.f, 0.f, 0.f};
            #pragma unroll
            for (int kb = 0; kb < 4; ++kb)
                c = __builtin_amdgcn_mfma_f32_16x16x32_bf16(a[kb], wl[(nt * 4 + kb) * 64], c, 0, 0, 0);
            float bias = bo[nt * 16 + r];
            #pragma unroll
            for (int i = 0; i < 4; ++i)
                out_u[(size_t)(base + kg * 4 + i) * OUT_DIM + nt * 16 + r] = c[i] + bias;
        }
    }
}

extern "C" void kernel_launch(void* const* d_in, const int* in_sizes, int n_in,
                              void* d_out, int out_size, void* d_ws, size_t ws_size,
                              hipStream_t stream)
{
    const float* x_user = (const float*)d_in[0];
    const float* x_item = (const float*)d_in[1];
    const float* W_proj = (const float*)d_in[2];
    const float* b_proj = (const float*)d_in[3];
    const float* al_uu  = (const float*)d_in[4];
    const float* ar_uu  = (const float*)d_in[5];
    const float* al_iu  = (const float*)d_in[6];
    const float* ar_iu  = (const float*)d_in[7];
    const float* al_ui  = (const float*)d_in[8];
    const float* ar_ui  = (const float*)d_in[9];
    const float* W_out  = (const float*)d_in[10];
    const float* b_out  = (const float*)d_in[11];
    const int* edges_uu = (const int*)d_in[12];
    const int* edges_iu = (const int*)d_in[13];
    const int* edges_ui = (const int*)d_in[14];

    char* ws = (char*)d_ws;
    unsigned short* h_u = (unsigned short*)(ws);                   // 12,800,000
    unsigned short* h_i = (unsigned short*)(ws + 12800000);        // 12,800,000
    unsigned short* Wpk = (unsigned short*)(ws + 25600000);        //    524,288 (8 copies)
    unsigned short* Wok = (unsigned short*)(ws + 26124288);        //     16,384
    int* cnt            = (int*)(ws + 26140672);                   //    600,000 (3 x 50000)
    int* bkt8           = (int*)(ws + 26740672);                   //  4,800,000 (3 x 50000 x 8, hot)
    int* bktx           = (int*)(ws + 31540672);                   // 14,400,000 (3 x 50000 x 24, cold)

    float* out_u = (float*)d_out;
    float* out_i = out_u + (size_t)N_USER * OUT_DIM;

    dim3 blk(256);
    // pack W (blocks 0..19) + zero cnt (blocks 20..605)
    pack_w_kernel<<<dim3(606), blk, 0, stream>>>(W_proj, W_out, Wpk, Wok, cnt);

    // fill (blocks 0..120, grid-stride) + proj (blocks 121..511) in one dispatch
    proj_kernel<<<dim3(FILL_GRID + PROJ_GRID), dim3(1024), 0, stream>>>(
        x_user, x_item, Wpk, b_proj, h_u, h_i,
        edges_uu, edges_iu, edges_ui, cnt, bkt8, bktx);

    epilogue_kernel<<<dim3(NSTRIP + 12500), blk, 0, stream>>>(
        h_u, h_i, cnt, bkt8, bktx, al_uu, ar_uu, al_iu, ar_iu, al_ui, ar_ui,
        Wok, b_out, out_u, out_i);
}